// Round 1
// baseline (300.430 us; speedup 1.0000x reference)
//
#include <hip/hip_runtime.h>

// RandomShift: out[row, t] = x[row, t - s] if 0 <= t-s < T else 0
// x: [256, 160000] float32, shifts: [256] int32; s = shifts[row] - 16000 (row-uniform).
//
// Memory-bound shifted copy (163.84 MB in + 163.84 MB out).
// V2 changes vs 267µs baseline:
//  - 8 floats/thread, 3-way row-uniform-ish branch:
//      interior: 2x unaligned global_load_dwordx4 (CDNA multi-dword loads need only
//                4B alignment) instead of 8 scalar loads
//      fully-out-of-range (the |s|<=16000 zero region, up to 10% of output):
//                pure vectorized zero stores, no loads at all
//      boundary: scalar predicated path (<=2 threads per row)
//  - nontemporal stores: out is touch-once; keep 164MB write stream out of L2/L3.

constexpr int T_LEN     = 160000;
constexpr int MAX_SHIFT = 16000;   // int(T * 0.1)
constexpr int ROWS      = 32 * 8;  // B * M
constexpr int VEC       = 8;       // floats per thread; T_LEN % VEC == 0

// float4 with only 4B alignment guarantee -> legal unaligned dwordx4 on gfx950
typedef float f4u __attribute__((ext_vector_type(4), aligned(4)));

__global__ __launch_bounds__(256) void RandomShift_33079838113837_kernel(
    const float* __restrict__ x,
    const int*   __restrict__ shifts,
    float*       __restrict__ out) {
    const int row = blockIdx.y;                    // 0..ROWS-1, wave-uniform
    const int s   = shifts[row] - MAX_SHIFT;       // row-uniform shift

    const float* __restrict__ xr   = x   + (size_t)row * T_LEN;
    float*       __restrict__ outr = out + (size_t)row * T_LEN;

    const int t0 = (blockIdx.x * blockDim.x + threadIdx.x) * VEC;
    if (t0 >= T_LEN) return;                       // T_LEN % VEC == 0, no partial vec

    const int src0 = t0 - s;

    f4u* __restrict__ o0 = (f4u*)(outr + t0);      // 32B-aligned (t0 % 8 == 0)
    f4u* __restrict__ o1 = (f4u*)(outr + t0 + 4);

    if (src0 >= 0 && src0 + VEC <= T_LEN) {
        // interior: whole 8-float window in range -> unaligned vector loads
        f4u a = *(const f4u*)(xr + src0);
        f4u b = *(const f4u*)(xr + src0 + 4);
        __builtin_nontemporal_store(a, o0);
        __builtin_nontemporal_store(b, o1);
    } else if (src0 + VEC <= 0 || src0 >= T_LEN) {
        // fully out of range: vectorized zero-fill, no loads
        f4u z = {0.0f, 0.0f, 0.0f, 0.0f};
        __builtin_nontemporal_store(z, o0);
        __builtin_nontemporal_store(z, o1);
    } else {
        // boundary straddle: <=2 threads per row, scalar predicated
#pragma unroll
        for (int j = 0; j < VEC; ++j) {
            const int src = src0 + j;
            outr[t0 + j] = (src >= 0 && src < T_LEN) ? xr[src] : 0.0f;
        }
    }
}

extern "C" void kernel_launch(void* const* d_in, const int* in_sizes, int n_in,
                              void* d_out, int out_size, void* d_ws, size_t ws_size,
                              hipStream_t stream) {
    const float* x      = (const float*)d_in[0];
    const int*   shifts = (const int*)d_in[1];
    float*       out    = (float*)d_out;

    const int vec_per_row = T_LEN / VEC;                   // 20000
    const int block = 256;
    dim3 grid((vec_per_row + block - 1) / block, ROWS, 1); // 79 x 256

    RandomShift_33079838113837_kernel<<<grid, block, 0, stream>>>(x, shifts, out);
}

// Round 2
// 273.813 us; speedup vs baseline: 1.0972x; 1.0972x over previous
//
#include <hip/hip_runtime.h>

// RandomShift: out[row, t] = x[row, t - s] if 0 <= t-s < T else 0
// x: [256, 160000] float32, shifts: [256] int32; s = shifts[row] - 16000 (row-uniform).
//
// Memory-bound shifted copy (163.84 MB in + 163.84 MB out).
// V3: V2 minus nontemporal stores. rocprof showed nt stores caused 44% HBM write
// amplification (WRITE_SIZE 236 MB vs 164 MB ideal) and throttled the write
// stream to ~2 TB/s (kernel 118 us @ 2.7 TB/s). Regular stores allocate in L2
// and write-combine into full lines. Keep: 8 floats/thread, zero-region
// store-only fast path, unaligned dwordx4 interior loads (load side showed NO
// amplification: FETCH 77 MB < 164 MB input, L3 absorbing re-reads).

constexpr int T_LEN     = 160000;
constexpr int MAX_SHIFT = 16000;   // int(T * 0.1)
constexpr int ROWS      = 32 * 8;  // B * M
constexpr int VEC       = 8;       // floats per thread; T_LEN % VEC == 0

// float4 with only 4B alignment guarantee -> legal unaligned dwordx4 on gfx950
typedef float f4u __attribute__((ext_vector_type(4), aligned(4)));

__global__ __launch_bounds__(256) void RandomShift_33079838113837_kernel(
    const float* __restrict__ x,
    const int*   __restrict__ shifts,
    float*       __restrict__ out) {
    const int row = blockIdx.y;                    // 0..ROWS-1, wave-uniform
    const int s   = shifts[row] - MAX_SHIFT;       // row-uniform shift

    const float* __restrict__ xr   = x   + (size_t)row * T_LEN;
    float*       __restrict__ outr = out + (size_t)row * T_LEN;

    const int t0 = (blockIdx.x * blockDim.x + threadIdx.x) * VEC;
    if (t0 >= T_LEN) return;                       // T_LEN % VEC == 0, no partial vec

    const int src0 = t0 - s;

    f4u* __restrict__ o0 = (f4u*)(outr + t0);      // 32B-aligned (t0 % 8 == 0)
    f4u* __restrict__ o1 = (f4u*)(outr + t0 + 4);

    if (src0 >= 0 && src0 + VEC <= T_LEN) {
        // interior: whole 8-float window in range -> unaligned vector loads
        f4u a = *(const f4u*)(xr + src0);
        f4u b = *(const f4u*)(xr + src0 + 4);
        *o0 = a;
        *o1 = b;
    } else if (src0 + VEC <= 0 || src0 >= T_LEN) {
        // fully out of range: vectorized zero-fill, no loads
        f4u z = {0.0f, 0.0f, 0.0f, 0.0f};
        *o0 = z;
        *o1 = z;
    } else {
        // boundary straddle: <=2 threads per row, scalar predicated
#pragma unroll
        for (int j = 0; j < VEC; ++j) {
            const int src = src0 + j;
            outr[t0 + j] = (src >= 0 && src < T_LEN) ? xr[src] : 0.0f;
        }
    }
}

extern "C" void kernel_launch(void* const* d_in, const int* in_sizes, int n_in,
                              void* d_out, int out_size, void* d_ws, size_t ws_size,
                              hipStream_t stream) {
    const float* x      = (const float*)d_in[0];
    const int*   shifts = (const int*)d_in[1];
    float*       out    = (float*)d_out;

    const int vec_per_row = T_LEN / VEC;                   // 20000
    const int block = 256;
    dim3 grid((vec_per_row + block - 1) / block, ROWS, 1); // 79 x 256

    RandomShift_33079838113837_kernel<<<grid, block, 0, stream>>>(x, shifts, out);
}